// Round 19
// baseline (39.569 us; speedup 1.0000x reference)
//
#include <hip/hip_runtime.h>
#include <hip/hip_fp16.h>

typedef _Float16 f16;
typedef __attribute__((ext_vector_type(8))) _Float16 f16x8;
typedef __attribute__((ext_vector_type(4))) _Float16 f16x4;
typedef __attribute__((ext_vector_type(4))) short s16x4;
typedef __attribute__((ext_vector_type(4))) float f32x4;
typedef __attribute__((ext_vector_type(2))) float f32x2;
typedef unsigned uint2v __attribute__((ext_vector_type(2)));

#define MFMA16(a,b,c) __builtin_amdgcn_mfma_f32_16x16x32_f16(a,b,c,0,0,0)
#define EXP2(x) __builtin_amdgcn_exp2f(x)
#define LOG2E 1.4426950408889634f

#define B_DIM 8
#define L_DIM 2048
#define D_DIM 128
#define NGRP 4
#define KVB 64
#define NTILES 8             // 512 kv per group / KVB
#define TILE_B 16384         // 64x128 f16, subtiled [kv4][d16][kv&3][16B-chunks]
#define P_ST 72              // P row stride (f16); 16-row slice reused across q2 passes
#define PLS_OFF 131072       // after 4 grp * 2 buf * 16KB staging
#define PLS_W 2304           // 16 * 72 * 2 bytes per wave
#define SLAB_ST 132
#define SMEM_B 149504        // staging + P slices; epilogue (137216) overlays

__device__ __forceinline__ unsigned ldsa(const void* p) {
    return (unsigned)(unsigned long long)(const __attribute__((address_space(3))) char*)p;
}

// VALU cross-lane reductions via gfx950 permlane swap builtins (R18-verified)
__device__ __forceinline__ float pl16_max(float x) {
    unsigned u = __float_as_uint(x);
    uint2v r = __builtin_amdgcn_permlane16_swap(u, u, false, false);
    return fmaxf(__uint_as_float(r[0]), __uint_as_float(r[1]));
}
__device__ __forceinline__ float pl32_max(float x) {
    unsigned u = __float_as_uint(x);
    uint2v r = __builtin_amdgcn_permlane32_swap(u, u, false, false);
    return fmaxf(__uint_as_float(r[0]), __uint_as_float(r[1]));
}
__device__ __forceinline__ float pl16_add(float x) {
    unsigned u = __float_as_uint(x);
    uint2v r = __builtin_amdgcn_permlane16_swap(u, u, false, false);
    return __uint_as_float(r[0]) + __uint_as_float(r[1]);
}
__device__ __forceinline__ float pl32_add(float x) {
    unsigned u = __float_as_uint(x);
    uint2v r = __builtin_amdgcn_permlane32_swap(u, u, false, false);
    return __uint_as_float(r[0]) + __uint_as_float(r[1]);
}

#define TRRD(d, a, O) asm volatile("ds_read_b64_tr_b16 %0, %1 offset:" O : "=v"(d) : "v"(a))
#define LGKM0() do { asm volatile("s_waitcnt lgkmcnt(0)" ::: "memory"); __builtin_amdgcn_sched_barrier(0); } while (0)
#define GLDS(gp, lp) __builtin_amdgcn_global_load_lds( \
    (const __attribute__((address_space(1))) unsigned int*)(gp), \
    (__attribute__((address_space(3))) unsigned int*)(lp), 16, 0, 0)

#define PVND(TL, TH, PA0, PA1, ND) { \
    union { s16x4 s2[2]; f16x8 v; } uu; uu.s2[0] = TL; uu.s2[1] = TH; \
    acc[0][ND] = MFMA16(PA0, uu.v, acc[0][ND]); \
    acc[1][ND] = MFMA16(PA1, uu.v, acc[1][ND]); }

#define PV_HALF(AREG, PA0, PA1, S0,S0b,S1,S1b,S2,S2b,S3,S3b, NDB) { \
    s16x4 t0l,t0h,t1l,t1h,t2l,t2h,t3l,t3h; \
    TRRD(t0l, AREG, S0);  TRRD(t0h, AREG, S0b); \
    TRRD(t1l, AREG, S1);  TRRD(t1h, AREG, S1b); \
    TRRD(t2l, AREG, S2);  TRRD(t2h, AREG, S2b); \
    TRRD(t3l, AREG, S3);  TRRD(t3h, AREG, S3b); \
    LGKM0(); \
    __builtin_amdgcn_s_setprio(1); \
    PVND(t0l, t0h, PA0, PA1, NDB+0); PVND(t1l, t1h, PA0, PA1, NDB+1); \
    PVND(t2l, t2h, PA0, PA1, NDB+2); PVND(t3l, t3h, PA0, PA1, NDB+3); \
    __builtin_amdgcn_s_setprio(0); }

// ---- pre-pass: V f32 -> f16 in chunk-permuted subtile order, one block per 64-kv tile ----
__global__ __launch_bounds__(256) void prep_v(const float* __restrict__ V, f16* __restrict__ ws) {
    const int blk = blockIdx.x;                    // b*32 + tt
    const float* src = V + (size_t)blk * (KVB * D_DIM);
    f16* dst = ws + (size_t)blk * (KVB * D_DIM);
    const int t = threadIdx.x;
    #pragma unroll
    for (int ii = 0; ii < 4; ++ii) {
        int lin = ii * 256 + t;
        int kv = lin >> 4, oct = lin & 15;         // oct = d/8
        const float* sp = src + kv * D_DIM + oct * 8;
        f32x4 a = *(const f32x4*)sp;
        f32x4 b = *(const f32x4*)(sp + 4);
        // chunk id for (kv, d0=oct*8): offset/16 = (kv>>2)*64 + (d0>>4)*8 + (kv&3)*2 + ((d0>>3)&1)
        int c = (kv >> 2) * 64 + (oct >> 1) * 8 + (kv & 3) * 2 + (oct & 1);
        union { f16 h[8]; f16x8 v; } u;
        #pragma unroll
        for (int k = 0; k < 4; ++k) { u.h[k] = (f16)a[k]; u.h[k + 4] = (f16)b[k]; }
        *(f16x8*)(dst + (size_t)c * 8) = u.v;
    }
}

__global__ __launch_bounds__(512, 2) void attn_fwd(
    const float* __restrict__ Q, const f16* __restrict__ ws, float* __restrict__ Out)
{
    __shared__ __align__(16) char smem[SMEM_B];

    const int tid  = threadIdx.x;
    const int wv   = tid >> 6;
    const int grp  = wv >> 1;      // kv group 0..3 (512 kv each)
    const int qw   = wv & 1;       // q half (32 rows)
    const int lane = tid & 63;
    const int lrow = lane & 15;
    const int g    = lane >> 4;

    const int blk = blockIdx.x;
    const int b   = blk & 7;
    const int q0  = (blk >> 3) * 64;

    char* grpbase = smem + grp * (2 * TILE_B);

    // ---- Q fragments: single-pass fp16, pre-scaled by log2(e) ----
    f16x8 qh[2][4];
    {
        const float* qb = Q + ((size_t)b * L_DIM + q0 + qw * 32) * D_DIM;
        #pragma unroll
        for (int q2 = 0; q2 < 2; ++q2) {
            const float* qp = qb + (size_t)(q2 * 16 + lrow) * D_DIM + g * 8;
            #pragma unroll
            for (int dt = 0; dt < 4; ++dt) {
                f32x4 f0 = *(const f32x4*)(qp + dt * 32);
                f32x4 f1 = *(const f32x4*)(qp + dt * 32 + 4);
                #pragma unroll
                for (int i = 0; i < 4; ++i) {
                    qh[q2][dt][i]     = (f16)(f0[i] * LOG2E);
                    qh[q2][dt][i + 4] = (f16)(f1[i] * LOG2E);
                }
            }
        }
    }

    f32x4 acc[2][8];
    #pragma unroll
    for (int q2 = 0; q2 < 2; ++q2)
        #pragma unroll
        for (int i = 0; i < 8; ++i) acc[q2][i] = (f32x4)0.0f;
    float m_run[2] = { -3.0e38f, -3.0e38f }, l_run[2] = { 0.0f, 0.0f };

    // QK A-frag lane offset (bytes within tile)
    const int qkoff = (lrow >> 2) * 1024 + (g >> 1) * 128 + (lrow & 3) * 32 + (g & 1) * 16;

    const f16* wsb = ws + (size_t)b * (32 * KVB * D_DIM);   // this batch's ws slice
    f16* pls = (f16*)(smem + PLS_OFF + wv * PLS_W);          // dedicated wave P slice

    // ---- prologue: DMA tile 0 into buf0 ----
    {
        const f16* w0 = wsb + (size_t)(grp * 8) * 8192 + (size_t)(qw * 512 + lane) * 8;
        char* ldst = grpbase + qw * 8192;
        #pragma unroll
        for (int i = 0; i < 8; ++i) GLDS(w0 + i * 512, ldst + i * 1024);
    }
    __syncthreads();

    for (int t = 0; t < NTILES; ++t) {
        const int c = t & 1;
        char* cur = grpbase + c * TILE_B;
        char* alt = grpbase + (c ^ 1) * TILE_B;

        // ---- issue DMA of tile t+1 into alt FIRST (alt dead since PV(t-1));
        //      latency hides under QK + softmax + PV of tile t ----
        if (t + 1 < NTILES) {
            const f16* wnt = wsb + (size_t)(grp * 8 + t + 1) * 8192 + (size_t)(qw * 512 + lane) * 8;
            char* ldst = alt + qw * 8192;
            #pragma unroll
            for (int i = 0; i < 8; ++i) GLDS(wnt + i * 512, ldst + i * 1024);
        }

        // ---- QK^T swapped: S^T[kv 64][q 32], fp16 1-pass (log2e-scaled) ----
        f32x4 s[2][4];
        #pragma unroll
        for (int q2 = 0; q2 < 2; ++q2)
            #pragma unroll
            for (int nt = 0; nt < 4; ++nt) s[q2][nt] = (f32x4)0.0f;
        __builtin_amdgcn_s_setprio(1);
        #pragma unroll
        for (int nt = 0; nt < 4; ++nt) {
            #pragma unroll
            for (int dt = 0; dt < 4; ++dt) {
                f16x8 a = *(const f16x8*)(cur + qkoff + nt * 4096 + dt * 256);
                s[0][nt] = MFMA16(a, qh[0][dt], s[0][nt]);
                s[1][nt] = MFMA16(a, qh[1][dt], s[1][nt]);
            }
        }
        __builtin_amdgcn_s_setprio(0);

        // ---- online softmax with defer-max (THR=11.5 in log2 units) ----
        float pm[2];
        #pragma unroll
        for (int q2 = 0; q2 < 2; ++q2) {
            float tm = s[q2][0][0];
            #pragma unroll
            for (int nt = 0; nt < 4; ++nt)
                #pragma unroll
                for (int r = 0; r < 4; ++r) tm = fmaxf(tm, s[q2][nt][r]);
            tm = pl16_max(tm);
            tm = pl32_max(tm);
            pm[q2] = tm;
        }
        bool need = (pm[0] > m_run[0] + 11.5f) || (pm[1] > m_run[1] + 11.5f);
        if (__any(need)) {
            float scl[2];
            #pragma unroll
            for (int q2 = 0; q2 < 2; ++q2) {
                float mnew = fmaxf(m_run[q2], pm[q2]);
                scl[q2]  = EXP2(m_run[q2] - mnew);
                m_run[q2] = mnew;
                l_run[q2] *= scl[q2];
            }
            float sr[2][4];
            #pragma unroll
            for (int r = 0; r < 4; ++r) {
                sr[0][r] = __shfl(scl[0], g * 4 + r);
                sr[1][r] = __shfl(scl[1], g * 4 + r);
            }
            #pragma unroll
            for (int q2 = 0; q2 < 2; ++q2)
                #pragma unroll
                for (int nd = 0; nd < 8; ++nd)
                    #pragma unroll
                    for (int r = 0; r < 4; ++r) acc[q2][nd][r] *= sr[q2][r];
        }
        #pragma unroll
        for (int q2 = 0; q2 < 2; ++q2) {
            float ps = 0.0f;
            #pragma unroll
            for (int nt = 0; nt < 4; ++nt)
                #pragma unroll
                for (int r = 0; r < 4; ++r) {
                    float p = EXP2(s[q2][nt][r] - m_run[q2]);
                    s[q2][nt][r] = p;
                    ps += p;
                }
            ps = pl16_add(ps);
            ps = pl32_add(ps);
            l_run[q2] += ps;
        }

        // ---- P -> dedicated LDS slice, two 16-row passes (q2=0 then q2=1);
        //      same-wave same-address DS ops are in-order, compiler tracks deps ----
        f16x8 pa00, pa01, pa10, pa11;
        #pragma unroll
        for (int nt = 0; nt < 4; ++nt) {
            f16x4 w = { (f16)s[0][nt][0], (f16)s[0][nt][1],
                        (f16)s[0][nt][2], (f16)s[0][nt][3] };
            *(f16x4*)(pls + (size_t)lrow * P_ST + nt * 16 + g * 4) = w;
        }
        pa00 = *(const f16x8*)(pls + (size_t)lrow * P_ST + g * 8);
        pa01 = *(const f16x8*)(pls + (size_t)lrow * P_ST + 32 + g * 8);
        #pragma unroll
        for (int nt = 0; nt < 4; ++nt) {
            f16x4 w = { (f16)s[1][nt][0], (f16)s[1][nt][1],
                        (f16)s[1][nt][2], (f16)s[1][nt][3] };
            *(f16x4*)(pls + (size_t)lrow * P_ST + nt * 16 + g * 4) = w;
        }
        pa10 = *(const f16x8*)(pls + (size_t)lrow * P_ST + g * 8);
        pa11 = *(const f16x8*)(pls + (size_t)lrow * P_ST + 32 + g * 8);

        // ---- PV via hardware transpose reads ----
        unsigned atr0 = ldsa(cur) + (unsigned)(g * 2048 + lrow * 8);
        unsigned atr1 = atr0 + 8192u;
        PV_HALF(atr0, pa00, pa10, "0","1024","128","1152","256","1280","384","1408", 0);
        PV_HALF(atr0, pa00, pa10, "512","1536","640","1664","768","1792","896","1920", 4);
        PV_HALF(atr1, pa01, pa11, "0","1024","128","1152","256","1280","384","1408", 0);
        PV_HALF(atr1, pa01, pa11, "512","1536","640","1664","768","1792","896","1920", 4);

        __syncthreads();   // drains vmcnt (DMA) + lgkm; next iter reads alt
    }

    // ---- cross-group merge (smem repurposed after final barrier) ----
    float* slab = (float*)smem;                          // [8 waves][32 q][SLAB_ST]
    float* mlp  = (float*)(smem + 8 * 32 * SLAB_ST * 4); // [8 waves][2][32]
    #pragma unroll
    for (int q2 = 0; q2 < 2; ++q2)
        #pragma unroll
        for (int nd = 0; nd < 8; ++nd)
            #pragma unroll
            for (int r = 0; r < 4; ++r)
                slab[(size_t)(wv * 32 + q2 * 16 + g * 4 + r) * SLAB_ST + nd * 16 + lrow] = acc[q2][nd][r];
    if (g == 0) {
        #pragma unroll
        for (int q2 = 0; q2 < 2; ++q2) {
            mlp[wv * 64 + q2 * 16 + lrow]      = m_run[q2];
            mlp[wv * 64 + 32 + q2 * 16 + lrow] = l_run[q2];
        }
    }
    __syncthreads();

    #pragma unroll
    for (int rr = 0; rr < 8; ++rr) {
        int row = wv * 8 + rr;
        int qws = row >> 5, ql = row & 31;
        float mg[4], M = -3.0e38f;
        #pragma unroll
        for (int gg = 0; gg < 4; ++gg) {
            mg[gg] = mlp[(gg * 2 + qws) * 64 + ql];
            M = fmaxf(M, mg[gg]);
        }
        float L = 0.0f, f[4];
        #pragma unroll
        for (int gg = 0; gg < 4; ++gg) {
            f[gg] = EXP2(mg[gg] - M);
            L += f[gg] * mlp[(gg * 2 + qws) * 64 + 32 + ql];
        }
        float inv = 1.0f / L;
        f32x2 o = { 0.0f, 0.0f };
        #pragma unroll
        for (int gg = 0; gg < 4; ++gg) {
            f32x2 v = *(const f32x2*)&slab[(size_t)((gg * 2 + qws) * 32 + ql) * SLAB_ST + lane * 2];
            o[0] += f[gg] * v[0];
            o[1] += f[gg] * v[1];
        }
        o[0] *= inv; o[1] *= inv;
        *(f32x2*)&Out[((size_t)b * L_DIM + q0 + row) * D_DIM + lane * 2] = o;
    }
}

extern "C" void kernel_launch(void* const* d_in, const int* in_sizes, int n_in,
                              void* d_out, int out_size, void* d_ws, size_t ws_size,
                              hipStream_t stream) {
    const float* Q = (const float*)d_in[0];
    const float* V = (const float*)d_in[1];
    float* Out     = (float*)d_out;
    f16* ws        = (f16*)d_ws;   // needs 4 MiB
    prep_v<<<dim3(B_DIM * (L_DIM / KVB)), dim3(256), 0, stream>>>(V, ws);
    attn_fwd<<<dim3(B_DIM * (L_DIM / 64)), dim3(512), 0, stream>>>(Q, ws, Out);
}

// Round 20
// 39.235 us; speedup vs baseline: 1.0085x; 1.0085x over previous
//
#include <hip/hip_runtime.h>
#include <hip/hip_fp16.h>

typedef _Float16 f16;
typedef __attribute__((ext_vector_type(8))) _Float16 f16x8;
typedef __attribute__((ext_vector_type(4))) _Float16 f16x4;
typedef __attribute__((ext_vector_type(4))) short s16x4;
typedef __attribute__((ext_vector_type(4))) float f32x4;
typedef __attribute__((ext_vector_type(2))) float f32x2;
typedef unsigned uint2v __attribute__((ext_vector_type(2)));

#define MFMA16(a,b,c) __builtin_amdgcn_mfma_f32_16x16x32_f16(a,b,c,0,0,0)
#define EXP2(x) __builtin_amdgcn_exp2f(x)
#define LOG2E 1.4426950408889634f

#define B_DIM 8
#define L_DIM 2048
#define D_DIM 128
#define NGRP 4
#define KVB 64
#define NTILES 8             // 512 kv per group / KVB
#define TILE_B 16384         // 64x128 f16, subtiled [kv4][d16][kv&3][16B-chunks]
#define P_ST 72              // P row stride (f16)
#define SLAB_ST 132
#define SMEM_B 137216        // staging 4*2*16384=131072; epilogue slabs 135168+2048

__device__ __forceinline__ unsigned ldsa(const void* p) {
    return (unsigned)(unsigned long long)(const __attribute__((address_space(3))) char*)p;
}

// VALU cross-lane reductions via gfx950 permlane swap builtins (R18-verified)
__device__ __forceinline__ float pl16_max(float x) {
    unsigned u = __float_as_uint(x);
    uint2v r = __builtin_amdgcn_permlane16_swap(u, u, false, false);
    return fmaxf(__uint_as_float(r[0]), __uint_as_float(r[1]));
}
__device__ __forceinline__ float pl32_max(float x) {
    unsigned u = __float_as_uint(x);
    uint2v r = __builtin_amdgcn_permlane32_swap(u, u, false, false);
    return fmaxf(__uint_as_float(r[0]), __uint_as_float(r[1]));
}
__device__ __forceinline__ float pl16_add(float x) {
    unsigned u = __float_as_uint(x);
    uint2v r = __builtin_amdgcn_permlane16_swap(u, u, false, false);
    return __uint_as_float(r[0]) + __uint_as_float(r[1]);
}
__device__ __forceinline__ float pl32_add(float x) {
    unsigned u = __float_as_uint(x);
    uint2v r = __builtin_amdgcn_permlane32_swap(u, u, false, false);
    return __uint_as_float(r[0]) + __uint_as_float(r[1]);
}

#define TRRD(d, a, O) asm volatile("ds_read_b64_tr_b16 %0, %1 offset:" O : "=v"(d) : "v"(a))
#define LGKM0() do { asm volatile("s_waitcnt lgkmcnt(0)" ::: "memory"); __builtin_amdgcn_sched_barrier(0); } while (0)
#define GLDS(gp, lp) __builtin_amdgcn_global_load_lds( \
    (const __attribute__((address_space(1))) unsigned int*)(gp), \
    (__attribute__((address_space(3))) unsigned int*)(lp), 16, 0, 0)

#define PVND(TL, TH, PA0, PA1, ND) { \
    union { s16x4 s2[2]; f16x8 v; } uu; uu.s2[0] = TL; uu.s2[1] = TH; \
    acc[0][ND] = MFMA16(PA0, uu.v, acc[0][ND]); \
    acc[1][ND] = MFMA16(PA1, uu.v, acc[1][ND]); }

#define PV_HALF(AREG, PA0, PA1, S0,S0b,S1,S1b,S2,S2b,S3,S3b, NDB) { \
    s16x4 t0l,t0h,t1l,t1h,t2l,t2h,t3l,t3h; \
    TRRD(t0l, AREG, S0);  TRRD(t0h, AREG, S0b); \
    TRRD(t1l, AREG, S1);  TRRD(t1h, AREG, S1b); \
    TRRD(t2l, AREG, S2);  TRRD(t2h, AREG, S2b); \
    TRRD(t3l, AREG, S3);  TRRD(t3h, AREG, S3b); \
    LGKM0(); \
    __builtin_amdgcn_s_setprio(1); \
    PVND(t0l, t0h, PA0, PA1, NDB+0); PVND(t1l, t1h, PA0, PA1, NDB+1); \
    PVND(t2l, t2h, PA0, PA1, NDB+2); PVND(t3l, t3h, PA0, PA1, NDB+3); \
    __builtin_amdgcn_s_setprio(0); }

// ---- pre-pass: V f32 -> f16 in chunk-permuted subtile order, one block per 64-kv tile ----
__global__ __launch_bounds__(256) void prep_v(const float* __restrict__ V, f16* __restrict__ ws) {
    const int blk = blockIdx.x;                    // b*32 + tt
    const float* src = V + (size_t)blk * (KVB * D_DIM);
    f16* dst = ws + (size_t)blk * (KVB * D_DIM);
    const int t = threadIdx.x;
    #pragma unroll
    for (int ii = 0; ii < 4; ++ii) {
        int lin = ii * 256 + t;
        int kv = lin >> 4, oct = lin & 15;         // oct = d/8
        const float* sp = src + kv * D_DIM + oct * 8;
        f32x4 a = *(const f32x4*)sp;
        f32x4 b = *(const f32x4*)(sp + 4);
        // chunk id for (kv, d0=oct*8): offset/16 = (kv>>2)*64 + (d0>>4)*8 + (kv&3)*2 + ((d0>>3)&1)
        int c = (kv >> 2) * 64 + (oct >> 1) * 8 + (kv & 3) * 2 + (oct & 1);
        union { f16 h[8]; f16x8 v; } u;
        #pragma unroll
        for (int k = 0; k < 4; ++k) { u.h[k] = (f16)a[k]; u.h[k + 4] = (f16)b[k]; }
        *(f16x8*)(dst + (size_t)c * 8) = u.v;
    }
}

__global__ __launch_bounds__(512, 2) void attn_fwd(
    const float* __restrict__ Q, const f16* __restrict__ ws, float* __restrict__ Out)
{
    __shared__ __align__(16) char smem[SMEM_B];

    const int tid  = threadIdx.x;
    const int wv   = tid >> 6;
    const int grp  = wv >> 1;      // kv group 0..3 (512 kv each)
    const int qw   = wv & 1;       // q half (32 rows)
    const int lane = tid & 63;
    const int lrow = lane & 15;
    const int g    = lane >> 4;

    const int blk = blockIdx.x;
    const int b   = blk & 7;
    const int q0  = (blk >> 3) * 64;

    char* grpbase = smem + grp * (2 * TILE_B);

    // ---- Q fragments: single-pass fp16, pre-scaled by log2(e) ----
    f16x8 qh[2][4];
    {
        const float* qb = Q + ((size_t)b * L_DIM + q0 + qw * 32) * D_DIM;
        #pragma unroll
        for (int q2 = 0; q2 < 2; ++q2) {
            const float* qp = qb + (size_t)(q2 * 16 + lrow) * D_DIM + g * 8;
            #pragma unroll
            for (int dt = 0; dt < 4; ++dt) {
                f32x4 f0 = *(const f32x4*)(qp + dt * 32);
                f32x4 f1 = *(const f32x4*)(qp + dt * 32 + 4);
                #pragma unroll
                for (int i = 0; i < 4; ++i) {
                    qh[q2][dt][i]     = (f16)(f0[i] * LOG2E);
                    qh[q2][dt][i + 4] = (f16)(f1[i] * LOG2E);
                }
            }
        }
    }

    f32x4 acc[2][8];
    #pragma unroll
    for (int q2 = 0; q2 < 2; ++q2)
        #pragma unroll
        for (int i = 0; i < 8; ++i) acc[q2][i] = (f32x4)0.0f;
    float m_run[2] = { -3.0e38f, -3.0e38f }, l_run[2] = { 0.0f, 0.0f };

    // QK A-frag lane offset (bytes within tile)
    const int qkoff = (lrow >> 2) * 1024 + (g >> 1) * 128 + (lrow & 3) * 32 + (g & 1) * 16;

    const f16* wsb = ws + (size_t)b * (32 * KVB * D_DIM);   // this batch's ws slice

    // ---- prologue: DMA tile 0 into buf0 ----
    {
        const f16* w0 = wsb + (size_t)(grp * 8) * 8192 + (size_t)(qw * 512 + lane) * 8;
        char* ldst = grpbase + qw * 8192;
        #pragma unroll
        for (int i = 0; i < 8; ++i) GLDS(w0 + i * 512, ldst + i * 1024);
    }
    __syncthreads();

    for (int t = 0; t < NTILES; ++t) {
        const int c = t & 1;
        char* cur = grpbase + c * TILE_B;
        char* alt = grpbase + (c ^ 1) * TILE_B;

        // ---- QK^T swapped: S^T[kv 64][q 32], fp16 1-pass (log2e-scaled) ----
        f32x4 s[2][4];
        #pragma unroll
        for (int q2 = 0; q2 < 2; ++q2)
            #pragma unroll
            for (int nt = 0; nt < 4; ++nt) s[q2][nt] = (f32x4)0.0f;
        __builtin_amdgcn_s_setprio(1);
        #pragma unroll
        for (int nt = 0; nt < 4; ++nt) {
            #pragma unroll
            for (int dt = 0; dt < 4; ++dt) {
                f16x8 a = *(const f16x8*)(cur + qkoff + nt * 4096 + dt * 256);
                s[0][nt] = MFMA16(a, qh[0][dt], s[0][nt]);
                s[1][nt] = MFMA16(a, qh[1][dt], s[1][nt]);
            }
        }
        __builtin_amdgcn_s_setprio(0);

        // ---- online softmax with defer-max (THR=11.5 log2); tree reductions ----
        float pm[2];
        #pragma unroll
        for (int q2 = 0; q2 < 2; ++q2) {
            float m01 = fmaxf(fmaxf(s[q2][0][0], s[q2][0][1]), fmaxf(s[q2][0][2], s[q2][0][3]));
            float m23 = fmaxf(fmaxf(s[q2][1][0], s[q2][1][1]), fmaxf(s[q2][1][2], s[q2][1][3]));
            float m45 = fmaxf(fmaxf(s[q2][2][0], s[q2][2][1]), fmaxf(s[q2][2][2], s[q2][2][3]));
            float m67 = fmaxf(fmaxf(s[q2][3][0], s[q2][3][1]), fmaxf(s[q2][3][2], s[q2][3][3]));
            float tm = fmaxf(fmaxf(m01, m23), fmaxf(m45, m67));
            tm = pl16_max(tm);
            tm = pl32_max(tm);
            pm[q2] = tm;
        }
        bool need = (pm[0] > m_run[0] + 11.5f) || (pm[1] > m_run[1] + 11.5f);
        if (__any(need)) {
            float scl[2];
            #pragma unroll
            for (int q2 = 0; q2 < 2; ++q2) {
                float mnew = fmaxf(m_run[q2], pm[q2]);
                scl[q2]  = EXP2(m_run[q2] - mnew);
                m_run[q2] = mnew;
                l_run[q2] *= scl[q2];
            }
            float sr[2][4];
            #pragma unroll
            for (int r = 0; r < 4; ++r) {
                sr[0][r] = __shfl(scl[0], g * 4 + r);
                sr[1][r] = __shfl(scl[1], g * 4 + r);
            }
            #pragma unroll
            for (int q2 = 0; q2 < 2; ++q2)
                #pragma unroll
                for (int nd = 0; nd < 8; ++nd)
                    #pragma unroll
                    for (int r = 0; r < 4; ++r) acc[q2][nd][r] *= sr[q2][r];
        }
        #pragma unroll
        for (int q2 = 0; q2 < 2; ++q2) {
            float pp[4];
            #pragma unroll
            for (int nt = 0; nt < 4; ++nt) {
                float p0 = EXP2(s[q2][nt][0] - m_run[q2]);
                float p1 = EXP2(s[q2][nt][1] - m_run[q2]);
                float p2 = EXP2(s[q2][nt][2] - m_run[q2]);
                float p3 = EXP2(s[q2][nt][3] - m_run[q2]);
                s[q2][nt][0] = p0; s[q2][nt][1] = p1;
                s[q2][nt][2] = p2; s[q2][nt][3] = p3;
                pp[nt] = (p0 + p1) + (p2 + p3);
            }
            float ps = (pp[0] + pp[1]) + (pp[2] + pp[3]);
            ps = pl16_add(ps);
            ps = pl32_add(ps);
            l_run[q2] += ps;
        }

        // ---- P -> LDS (dead half of alt buffer), read back as A-frags ----
        f16* pls = (f16*)(alt + qw * 8192);
        #pragma unroll
        for (int q2 = 0; q2 < 2; ++q2) {
            #pragma unroll
            for (int nt = 0; nt < 4; ++nt) {
                f16x4 w = { (f16)s[q2][nt][0], (f16)s[q2][nt][1],
                            (f16)s[q2][nt][2], (f16)s[q2][nt][3] };
                *(f16x4*)(pls + (size_t)(q2 * 16 + lrow) * P_ST + nt * 16 + g * 4) = w;
            }
        }
        f16x8 pa00, pa01, pa10, pa11;
        pa00 = *(const f16x8*)(pls + (size_t)(lrow) * P_ST + g * 8);
        pa01 = *(const f16x8*)(pls + (size_t)(lrow) * P_ST + 32 + g * 8);
        pa10 = *(const f16x8*)(pls + (size_t)(16 + lrow) * P_ST + g * 8);
        pa11 = *(const f16x8*)(pls + (size_t)(16 + lrow) * P_ST + 32 + g * 8);
        LGKM0();   // P reads landed in regs -> safe to DMA-overwrite the slice

        // ---- issue DMA staging of tile t+1 into alt (stays in flight under PV) ----
        if (t + 1 < NTILES) {
            const f16* wnt = wsb + (size_t)(grp * 8 + t + 1) * 8192 + (size_t)(qw * 512 + lane) * 8;
            char* ldst = alt + qw * 8192;
            #pragma unroll
            for (int i = 0; i < 8; ++i) GLDS(wnt + i * 512, ldst + i * 1024);
        }

        // ---- PV via hardware transpose reads ----
        unsigned atr0 = ldsa(cur) + (unsigned)(g * 2048 + lrow * 8);
        unsigned atr1 = atr0 + 8192u;
        PV_HALF(atr0, pa00, pa10, "0","1024","128","1152","256","1280","384","1408", 0);
        PV_HALF(atr0, pa00, pa10, "512","1536","640","1664","768","1792","896","1920", 4);
        PV_HALF(atr1, pa01, pa11, "0","1024","128","1152","256","1280","384","1408", 0);
        PV_HALF(atr1, pa01, pa11, "512","1536","640","1664","768","1792","896","1920", 4);

        __syncthreads();   // drains vmcnt (DMA) + lgkm; next iter reads alt
    }

    // ---- cross-group merge (smem repurposed after final barrier) ----
    float* slab = (float*)smem;                          // [8 waves][32 q][SLAB_ST]
    float* mlp  = (float*)(smem + 8 * 32 * SLAB_ST * 4); // [8 waves][2][32]
    #pragma unroll
    for (int q2 = 0; q2 < 2; ++q2)
        #pragma unroll
        for (int nd = 0; nd < 8; ++nd)
            #pragma unroll
            for (int r = 0; r < 4; ++r)
                slab[(size_t)(wv * 32 + q2 * 16 + g * 4 + r) * SLAB_ST + nd * 16 + lrow] = acc[q2][nd][r];
    if (g == 0) {
        #pragma unroll
        for (int q2 = 0; q2 < 2; ++q2) {
            mlp[wv * 64 + q2 * 16 + lrow]      = m_run[q2];
            mlp[wv * 64 + 32 + q2 * 16 + lrow] = l_run[q2];
        }
    }
    __syncthreads();

    #pragma unroll
    for (int rr = 0; rr < 8; ++rr) {
        int row = wv * 8 + rr;
        int qws = row >> 5, ql = row & 31;
        float mg[4], M = -3.0e38f;
        #pragma unroll
        for (int gg = 0; gg < 4; ++gg) {
            mg[gg] = mlp[(gg * 2 + qws) * 64 + ql];
            M = fmaxf(M, mg[gg]);
        }
        float L = 0.0f, f[4];
        #pragma unroll
        for (int gg = 0; gg < 4; ++gg) {
            f[gg] = EXP2(mg[gg] - M);
            L += f[gg] * mlp[(gg * 2 + qws) * 64 + 32 + ql];
        }
        float inv = 1.0f / L;
        f32x2 o = { 0.0f, 0.0f };
        #pragma unroll
        for (int gg = 0; gg < 4; ++gg) {
            f32x2 v = *(const f32x2*)&slab[(size_t)((gg * 2 + qws) * 32 + ql) * SLAB_ST + lane * 2];
            o[0] += f[gg] * v[0];
            o[1] += f[gg] * v[1];
        }
        o[0] *= inv; o[1] *= inv;
        *(f32x2*)&Out[((size_t)b * L_DIM + q0 + row) * D_DIM + lane * 2] = o;
    }
}

extern "C" void kernel_launch(void* const* d_in, const int* in_sizes, int n_in,
                              void* d_out, int out_size, void* d_ws, size_t ws_size,
                              hipStream_t stream) {
    const float* Q = (const float*)d_in[0];
    const float* V = (const float*)d_in[1];
    float* Out     = (float*)d_out;
    f16* ws        = (f16*)d_ws;   // needs 4 MiB
    prep_v<<<dim3(B_DIM * (L_DIM / KVB)), dim3(256), 0, stream>>>(V, ws);
    attn_fwd<<<dim3(B_DIM * (L_DIM / 64)), dim3(512), 0, stream>>>(Q, ws, Out);
}

// Round 21
// 37.854 us; speedup vs baseline: 1.0453x; 1.0365x over previous
//
#include <hip/hip_runtime.h>
#include <hip/hip_fp16.h>

typedef _Float16 f16;
typedef __attribute__((ext_vector_type(8))) _Float16 f16x8;
typedef __attribute__((ext_vector_type(4))) _Float16 f16x4;
typedef __attribute__((ext_vector_type(4))) short s16x4;
typedef __attribute__((ext_vector_type(4))) float f32x4;
typedef __attribute__((ext_vector_type(2))) float f32x2;
typedef unsigned uint2v __attribute__((ext_vector_type(2)));

#define MFMA16(a,b,c) __builtin_amdgcn_mfma_f32_16x16x32_f16(a,b,c,0,0,0)
#define EXP2(x) __builtin_amdgcn_exp2f(x)
#define LOG2E 1.4426950408889634f

#define B_DIM 8
#define L_DIM 2048
#define D_DIM 128
#define NGRP 4
#define KVB 64
#define NTILES 8             // 512 kv per group / KVB
#define TILE_B 16384         // 64x128 f16, subtiled [kv4][d16][kv&3][16B-chunks]
#define SLAB_ST 132
#define SMEM_B 137216        // staging 4*2*16384=131072; epilogue slabs 135168+2048

__device__ __forceinline__ unsigned ldsa(const void* p) {
    return (unsigned)(unsigned long long)(const __attribute__((address_space(3))) char*)p;
}

// VALU cross-lane reductions via gfx950 permlane swap builtins (R18-verified)
__device__ __forceinline__ float pl16_max(float x) {
    unsigned u = __float_as_uint(x);
    uint2v r = __builtin_amdgcn_permlane16_swap(u, u, false, false);
    return fmaxf(__uint_as_float(r[0]), __uint_as_float(r[1]));
}
__device__ __forceinline__ float pl32_max(float x) {
    unsigned u = __float_as_uint(x);
    uint2v r = __builtin_amdgcn_permlane32_swap(u, u, false, false);
    return fmaxf(__uint_as_float(r[0]), __uint_as_float(r[1]));
}
__device__ __forceinline__ float pl16_add(float x) {
    unsigned u = __float_as_uint(x);
    uint2v r = __builtin_amdgcn_permlane16_swap(u, u, false, false);
    return __uint_as_float(r[0]) + __uint_as_float(r[1]);
}
__device__ __forceinline__ float pl32_add(float x) {
    unsigned u = __float_as_uint(x);
    uint2v r = __builtin_amdgcn_permlane32_swap(u, u, false, false);
    return __uint_as_float(r[0]) + __uint_as_float(r[1]);
}

// RNE pack of two f32 -> one u32 of two f16 (same numerics as the old LDS path)
__device__ __forceinline__ unsigned pkh(float lo, float hi) {
    union { f16 h[2]; unsigned u; } c;
    c.h[0] = (f16)lo; c.h[1] = (f16)hi;
    return c.u;
}

#define TRRD(d, a, O) asm volatile("ds_read_b64_tr_b16 %0, %1 offset:" O : "=v"(d) : "v"(a))
#define LGKM0() do { asm volatile("s_waitcnt lgkmcnt(0)" ::: "memory"); __builtin_amdgcn_sched_barrier(0); } while (0)
#define GLDS(gp, lp) __builtin_amdgcn_global_load_lds( \
    (const __attribute__((address_space(1))) unsigned int*)(gp), \
    (__attribute__((address_space(3))) unsigned int*)(lp), 16, 0, 0)

#define PVND(TL, TH, PA0, PA1, ND) { \
    union { s16x4 s2[2]; f16x8 v; } uu; uu.s2[0] = TL; uu.s2[1] = TH; \
    acc[0][ND] = MFMA16(PA0, uu.v, acc[0][ND]); \
    acc[1][ND] = MFMA16(PA1, uu.v, acc[1][ND]); }

#define PV_HALF(AREG, PA0, PA1, S0,S0b,S1,S1b,S2,S2b,S3,S3b, NDB) { \
    s16x4 t0l,t0h,t1l,t1h,t2l,t2h,t3l,t3h; \
    TRRD(t0l, AREG, S0);  TRRD(t0h, AREG, S0b); \
    TRRD(t1l, AREG, S1);  TRRD(t1h, AREG, S1b); \
    TRRD(t2l, AREG, S2);  TRRD(t2h, AREG, S2b); \
    TRRD(t3l, AREG, S3);  TRRD(t3h, AREG, S3b); \
    LGKM0(); \
    __builtin_amdgcn_s_setprio(1); \
    PVND(t0l, t0h, PA0, PA1, NDB+0); PVND(t1l, t1h, PA0, PA1, NDB+1); \
    PVND(t2l, t2h, PA0, PA1, NDB+2); PVND(t3l, t3h, PA0, PA1, NDB+3); \
    __builtin_amdgcn_s_setprio(0); }

// ---- pre-pass: V f32 -> f16 in chunk-permuted subtile order, one block per 64-kv tile ----
__global__ __launch_bounds__(256) void prep_v(const float* __restrict__ V, f16* __restrict__ ws) {
    const int blk = blockIdx.x;                    // b*32 + tt
    const float* src = V + (size_t)blk * (KVB * D_DIM);
    f16* dst = ws + (size_t)blk * (KVB * D_DIM);
    const int t = threadIdx.x;
    #pragma unroll
    for (int ii = 0; ii < 4; ++ii) {
        int lin = ii * 256 + t;
        int kv = lin >> 4, oct = lin & 15;         // oct = d/8
        const float* sp = src + kv * D_DIM + oct * 8;
        f32x4 a = *(const f32x4*)sp;
        f32x4 b = *(const f32x4*)(sp + 4);
        // chunk id for (kv, d0=oct*8): offset/16 = (kv>>2)*64 + (d0>>4)*8 + (kv&3)*2 + ((d0>>3)&1)
        int c = (kv >> 2) * 64 + (oct >> 1) * 8 + (kv & 3) * 2 + (oct & 1);
        union { f16 h[8]; f16x8 v; } u;
        #pragma unroll
        for (int k = 0; k < 4; ++k) { u.h[k] = (f16)a[k]; u.h[k + 4] = (f16)b[k]; }
        *(f16x8*)(dst + (size_t)c * 8) = u.v;
    }
}

__global__ __launch_bounds__(512, 2) void attn_fwd(
    const float* __restrict__ Q, const f16* __restrict__ ws, float* __restrict__ Out)
{
    __shared__ __align__(16) char smem[SMEM_B];

    const int tid  = threadIdx.x;
    const int wv   = tid >> 6;
    const int grp  = wv >> 1;      // kv group 0..3 (512 kv each)
    const int qw   = wv & 1;       // q half (32 rows)
    const int lane = tid & 63;
    const int lrow = lane & 15;
    const int g    = lane >> 4;

    const int blk = blockIdx.x;
    const int b   = blk & 7;
    const int q0  = (blk >> 3) * 64;

    char* grpbase = smem + grp * (2 * TILE_B);

    // ---- Q fragments: single-pass fp16, pre-scaled by log2(e) ----
    f16x8 qh[2][4];
    {
        const float* qb = Q + ((size_t)b * L_DIM + q0 + qw * 32) * D_DIM;
        #pragma unroll
        for (int q2 = 0; q2 < 2; ++q2) {
            const float* qp = qb + (size_t)(q2 * 16 + lrow) * D_DIM + g * 8;
            #pragma unroll
            for (int dt = 0; dt < 4; ++dt) {
                f32x4 f0 = *(const f32x4*)(qp + dt * 32);
                f32x4 f1 = *(const f32x4*)(qp + dt * 32 + 4);
                #pragma unroll
                for (int i = 0; i < 4; ++i) {
                    qh[q2][dt][i]     = (f16)(f0[i] * LOG2E);
                    qh[q2][dt][i + 4] = (f16)(f1[i] * LOG2E);
                }
            }
        }
    }

    f32x4 acc[2][8];
    #pragma unroll
    for (int q2 = 0; q2 < 2; ++q2)
        #pragma unroll
        for (int i = 0; i < 8; ++i) acc[q2][i] = (f32x4)0.0f;
    float m_run[2] = { -3.0e38f, -3.0e38f }, l_run[2] = { 0.0f, 0.0f };

    // QK A-frag lane offset (bytes within tile)
    const int qkoff = (lrow >> 2) * 1024 + (g >> 1) * 128 + (lrow & 3) * 32 + (g & 1) * 16;

    const f16* wsb = ws + (size_t)b * (32 * KVB * D_DIM);   // this batch's ws slice

    // ---- prologue: DMA tile 0 into buf0 ----
    {
        const f16* w0 = wsb + (size_t)(grp * 8) * 8192 + (size_t)(qw * 512 + lane) * 8;
        char* ldst = grpbase + qw * 8192;
        #pragma unroll
        for (int i = 0; i < 8; ++i) GLDS(w0 + i * 512, ldst + i * 1024);
    }
    __syncthreads();

    for (int t = 0; t < NTILES; ++t) {
        const int c = t & 1;
        char* cur = grpbase + c * TILE_B;
        char* alt = grpbase + (c ^ 1) * TILE_B;

        // ---- QK^T swapped: S^T[kv 64][q 32], fp16 1-pass (log2e-scaled) ----
        f32x4 s[2][4];
        #pragma unroll
        for (int q2 = 0; q2 < 2; ++q2)
            #pragma unroll
            for (int nt = 0; nt < 4; ++nt) s[q2][nt] = (f32x4)0.0f;
        __builtin_amdgcn_s_setprio(1);
        #pragma unroll
        for (int nt = 0; nt < 4; ++nt) {
            #pragma unroll
            for (int dt = 0; dt < 4; ++dt) {
                f16x8 a = *(const f16x8*)(cur + qkoff + nt * 4096 + dt * 256);
                s[0][nt] = MFMA16(a, qh[0][dt], s[0][nt]);
                s[1][nt] = MFMA16(a, qh[1][dt], s[1][nt]);
            }
        }
        __builtin_amdgcn_s_setprio(0);

        // ---- online softmax with defer-max (THR=11.5 in log2 units) ----
        float pm[2];
        #pragma unroll
        for (int q2 = 0; q2 < 2; ++q2) {
            float tm = s[q2][0][0];
            #pragma unroll
            for (int nt = 0; nt < 4; ++nt)
                #pragma unroll
                for (int r = 0; r < 4; ++r) tm = fmaxf(tm, s[q2][nt][r]);
            tm = pl16_max(tm);
            tm = pl32_max(tm);
            pm[q2] = tm;
        }
        bool need = (pm[0] > m_run[0] + 11.5f) || (pm[1] > m_run[1] + 11.5f);
        if (__any(need)) {
            float scl[2];
            #pragma unroll
            for (int q2 = 0; q2 < 2; ++q2) {
                float mnew = fmaxf(m_run[q2], pm[q2]);
                scl[q2]  = EXP2(m_run[q2] - mnew);
                m_run[q2] = mnew;
                l_run[q2] *= scl[q2];
            }
            float sr[2][4];
            #pragma unroll
            for (int r = 0; r < 4; ++r) {
                sr[0][r] = __shfl(scl[0], g * 4 + r);
                sr[1][r] = __shfl(scl[1], g * 4 + r);
            }
            #pragma unroll
            for (int q2 = 0; q2 < 2; ++q2)
                #pragma unroll
                for (int nd = 0; nd < 8; ++nd)
                    #pragma unroll
                    for (int r = 0; r < 4; ++r) acc[q2][nd][r] *= sr[q2][r];
        }
        #pragma unroll
        for (int q2 = 0; q2 < 2; ++q2) {
            float ps = 0.0f;
            #pragma unroll
            for (int nt = 0; nt < 4; ++nt)
                #pragma unroll
                for (int r = 0; r < 4; ++r) {
                    float p = EXP2(s[q2][nt][r] - m_run[q2]);
                    s[q2][nt][r] = p;
                    ps += p;
                }
            ps = pl16_add(ps);
            ps = pl32_add(ps);
            l_run[q2] += ps;
        }

        // ---- P -> A-frags fully in-register via permlane swaps (T12; no LDS) ----
        // src lane (lrow,gs) holds P[lrow][nt*16+gs*4+r]; dest lane (lrow,g) word w
        // of pa[kk] = pack(y[2kk+(g>>1)][w&1]) from row 2(g&1)+(w>>1).
        // (u,v)=swap32(a,b); (wA,wB)=swap16(u,v) gives rows [a@0,a@2,b@0,b@2]
        // (= word h) and [a@1,a@3,b@1,b@3] (= word 2+h), a=y[2kk][h], b=y[2kk+1][h].
        f16x8 pa00, pa01, pa10, pa11;
        {
            unsigned y0[4][2], y1[4][2];
            #pragma unroll
            for (int nt = 0; nt < 4; ++nt) {
                y0[nt][0] = pkh(s[0][nt][0], s[0][nt][1]);
                y0[nt][1] = pkh(s[0][nt][2], s[0][nt][3]);
                y1[nt][0] = pkh(s[1][nt][0], s[1][nt][1]);
                y1[nt][1] = pkh(s[1][nt][2], s[1][nt][3]);
            }
            union U8 { unsigned w[4]; f16x8 v; };
            U8 a00, a01, a10, a11;
            #pragma unroll
            for (int h = 0; h < 2; ++h) {
                uint2v t1 = __builtin_amdgcn_permlane32_swap(y0[0][h], y0[1][h], false, false);
                uint2v t2 = __builtin_amdgcn_permlane16_swap(t1[0], t1[1], false, false);
                a00.w[h] = t2[0]; a00.w[2 + h] = t2[1];
                uint2v t3 = __builtin_amdgcn_permlane32_swap(y0[2][h], y0[3][h], false, false);
                uint2v t4 = __builtin_amdgcn_permlane16_swap(t3[0], t3[1], false, false);
                a01.w[h] = t4[0]; a01.w[2 + h] = t4[1];
                uint2v t5 = __builtin_amdgcn_permlane32_swap(y1[0][h], y1[1][h], false, false);
                uint2v t6 = __builtin_amdgcn_permlane16_swap(t5[0], t5[1], false, false);
                a10.w[h] = t6[0]; a10.w[2 + h] = t6[1];
                uint2v t7 = __builtin_amdgcn_permlane32_swap(y1[2][h], y1[3][h], false, false);
                uint2v t8 = __builtin_amdgcn_permlane16_swap(t7[0], t7[1], false, false);
                a11.w[h] = t8[0]; a11.w[2 + h] = t8[1];
            }
            pa00 = a00.v; pa01 = a01.v; pa10 = a10.v; pa11 = a11.v;
        }

        // ---- issue DMA staging of tile t+1 into alt (alt dead since PV(t-1)) ----
        if (t + 1 < NTILES) {
            const f16* wnt = wsb + (size_t)(grp * 8 + t + 1) * 8192 + (size_t)(qw * 512 + lane) * 8;
            char* ldst = alt + qw * 8192;
            #pragma unroll
            for (int i = 0; i < 8; ++i) GLDS(wnt + i * 512, ldst + i * 1024);
        }

        // ---- PV via hardware transpose reads ----
        unsigned atr0 = ldsa(cur) + (unsigned)(g * 2048 + lrow * 8);
        unsigned atr1 = atr0 + 8192u;
        PV_HALF(atr0, pa00, pa10, "0","1024","128","1152","256","1280","384","1408", 0);
        PV_HALF(atr0, pa00, pa10, "512","1536","640","1664","768","1792","896","1920", 4);
        PV_HALF(atr1, pa01, pa11, "0","1024","128","1152","256","1280","384","1408", 0);
        PV_HALF(atr1, pa01, pa11, "512","1536","640","1664","768","1792","896","1920", 4);

        __syncthreads();   // drains vmcnt (DMA) + lgkm; next iter reads alt
    }

    // ---- cross-group merge (smem repurposed after final barrier) ----
    float* slab = (float*)smem;                          // [8 waves][32 q][SLAB_ST]
    float* mlp  = (float*)(smem + 8 * 32 * SLAB_ST * 4); // [8 waves][2][32]
    #pragma unroll
    for (int q2 = 0; q2 < 2; ++q2)
        #pragma unroll
        for (int nd = 0; nd < 8; ++nd)
            #pragma unroll
            for (int r = 0; r < 4; ++r)
                slab[(size_t)(wv * 32 + q2 * 16 + g * 4 + r) * SLAB_ST + nd * 16 + lrow] = acc[q2][nd][r];
    if (g == 0) {
        #pragma unroll
        for (int q2 = 0; q2 < 2; ++q2) {
            mlp[wv * 64 + q2 * 16 + lrow]      = m_run[q2];
            mlp[wv * 64 + 32 + q2 * 16 + lrow] = l_run[q2];
        }
    }
    __syncthreads();

    #pragma unroll
    for (int rr = 0; rr < 8; ++rr) {
        int row = wv * 8 + rr;
        int qws = row >> 5, ql = row & 31;
        float mg[4], M = -3.0e38f;
        #pragma unroll
        for (int gg = 0; gg < 4; ++gg) {
            mg[gg] = mlp[(gg * 2 + qws) * 64 + ql];
            M = fmaxf(M, mg[gg]);
        }
        float L = 0.0f, f[4];
        #pragma unroll
        for (int gg = 0; gg < 4; ++gg) {
            f[gg] = EXP2(mg[gg] - M);
            L += f[gg] * mlp[(gg * 2 + qws) * 64 + 32 + ql];
        }
        float inv = 1.0f / L;
        f32x2 o = { 0.0f, 0.0f };
        #pragma unroll
        for (int gg = 0; gg < 4; ++gg) {
            f32x2 v = *(const f32x2*)&slab[(size_t)((gg * 2 + qws) * 32 + ql) * SLAB_ST + lane * 2];
            o[0] += f[gg] * v[0];
            o[1] += f[gg] * v[1];
        }
        o[0] *= inv; o[1] *= inv;
        *(f32x2*)&Out[((size_t)b * L_DIM + q0 + row) * D_DIM + lane * 2] = o;
    }
}

extern "C" void kernel_launch(void* const* d_in, const int* in_sizes, int n_in,
                              void* d_out, int out_size, void* d_ws, size_t ws_size,
                              hipStream_t stream) {
    const float* Q = (const float*)d_in[0];
    const float* V = (const float*)d_in[1];
    float* Out     = (float*)d_out;
    f16* ws        = (f16*)d_ws;   // needs 4 MiB
    prep_v<<<dim3(B_DIM * (L_DIM / KVB)), dim3(256), 0, stream>>>(V, ws);
    attn_fwd<<<dim3(B_DIM * (L_DIM / 64)), dim3(512), 0, stream>>>(Q, ws, Out);
}

// Round 23
// 37.605 us; speedup vs baseline: 1.0523x; 1.0066x over previous
//
#include <hip/hip_runtime.h>
#include <hip/hip_fp16.h>

typedef _Float16 f16;
typedef __attribute__((ext_vector_type(8))) _Float16 f16x8;
typedef __attribute__((ext_vector_type(4))) _Float16 f16x4;
typedef __attribute__((ext_vector_type(4))) short s16x4;
typedef __attribute__((ext_vector_type(4))) float f32x4;
typedef __attribute__((ext_vector_type(2))) float f32x2;
typedef unsigned uint2v __attribute__((ext_vector_type(2)));

#define MFMA16(a,b,c) __builtin_amdgcn_mfma_f32_16x16x32_f16(a,b,c,0,0,0)
#define EXP2(x) __builtin_amdgcn_exp2f(x)
#define LOG2E 1.4426950408889634f

#define B_DIM 8
#define L_DIM 2048
#define D_DIM 128
#define NGRP 4
#define KVB 64
#define NTILES 8             // 512 kv per group / KVB
#define TILE_B 16384         // 64x128 f16, subtiled [kv4][d16][kv&3][16B-chunks]
#define SLAB_ST 132
#define SMEM_B 137216        // staging 4*2*16384=131072; epilogue slabs 135168+2048

__device__ __forceinline__ unsigned ldsa(const void* p) {
    return (unsigned)(unsigned long long)(const __attribute__((address_space(3))) char*)p;
}

// VALU cross-lane reductions via gfx950 permlane swap builtins (R18-verified)
__device__ __forceinline__ float pl16_max(float x) {
    unsigned u = __float_as_uint(x);
    uint2v r = __builtin_amdgcn_permlane16_swap(u, u, false, false);
    return fmaxf(__uint_as_float(r[0]), __uint_as_float(r[1]));
}
__device__ __forceinline__ float pl32_max(float x) {
    unsigned u = __float_as_uint(x);
    uint2v r = __builtin_amdgcn_permlane32_swap(u, u, false, false);
    return fmaxf(__uint_as_float(r[0]), __uint_as_float(r[1]));
}
__device__ __forceinline__ float pl16_add(float x) {
    unsigned u = __float_as_uint(x);
    uint2v r = __builtin_amdgcn_permlane16_swap(u, u, false, false);
    return __uint_as_float(r[0]) + __uint_as_float(r[1]);
}
__device__ __forceinline__ float pl32_add(float x) {
    unsigned u = __float_as_uint(x);
    uint2v r = __builtin_amdgcn_permlane32_swap(u, u, false, false);
    return __uint_as_float(r[0]) + __uint_as_float(r[1]);
}

// RNE pack of two f32 -> one u32 of two f16
__device__ __forceinline__ unsigned pkh(float lo, float hi) {
    union { f16 h[2]; unsigned u; } c;
    c.h[0] = (f16)lo; c.h[1] = (f16)hi;
    return c.u;
}

#define TRRD(d, a, O) asm volatile("ds_read_b64_tr_b16 %0, %1 offset:" O : "=v"(d) : "v"(a))
#define LGKMW(N) do { asm volatile("s_waitcnt lgkmcnt(" #N ")" ::: "memory"); __builtin_amdgcn_sched_barrier(0); } while (0)
#define GLDS(gp, lp) __builtin_amdgcn_global_load_lds( \
    (const __attribute__((address_space(1))) unsigned int*)(gp), \
    (__attribute__((address_space(3))) unsigned int*)(lp), 16, 0, 0)

#define PVND(TL, TH, PA0, PA1, ND) { \
    union { s16x4 s2[2]; f16x8 v; } uu; uu.s2[0] = TL; uu.s2[1] = TH; \
    acc[0][ND] = MFMA16(PA0, uu.v, acc[0][ND]); \
    acc[1][ND] = MFMA16(PA1, uu.v, acc[1][ND]); }

#define TR8(arr, AREG, S0,S0b,S1,S1b,S2,S2b,S3,S3b) \
    TRRD(arr[0], AREG, S0);  TRRD(arr[1], AREG, S0b); \
    TRRD(arr[2], AREG, S1);  TRRD(arr[3], AREG, S1b); \
    TRRD(arr[4], AREG, S2);  TRRD(arr[5], AREG, S2b); \
    TRRD(arr[6], AREG, S3);  TRRD(arr[7], AREG, S3b);

#define MM8(arr, PA0, PA1, NDB) \
    __builtin_amdgcn_s_setprio(1); \
    PVND(arr[0], arr[1], PA0, PA1, NDB+0); PVND(arr[2], arr[3], PA0, PA1, NDB+1); \
    PVND(arr[4], arr[5], PA0, PA1, NDB+2); PVND(arr[6], arr[7], PA0, PA1, NDB+3); \
    __builtin_amdgcn_s_setprio(0);

// ---- pre-pass: V f32 -> f16 in chunk-permuted subtile order, one block per 64-kv tile ----
__global__ __launch_bounds__(256) void prep_v(const float* __restrict__ V, f16* __restrict__ ws) {
    const int blk = blockIdx.x;                    // b*32 + tt
    const float* src = V + (size_t)blk * (KVB * D_DIM);
    f16* dst = ws + (size_t)blk * (KVB * D_DIM);
    const int t = threadIdx.x;
    #pragma unroll
    for (int ii = 0; ii < 4; ++ii) {
        int lin = ii * 256 + t;
        int kv = lin >> 4, oct = lin & 15;         // oct = d/8
        const float* sp = src + kv * D_DIM + oct * 8;
        f32x4 a = *(const f32x4*)sp;
        f32x4 b = *(const f32x4*)(sp + 4);
        // chunk id for (kv, d0=oct*8): offset/16 = (kv>>2)*64 + (d0>>4)*8 + (kv&3)*2 + ((d0>>3)&1)
        int c = (kv >> 2) * 64 + (oct >> 1) * 8 + (kv & 3) * 2 + (oct & 1);
        union { f16 h[8]; f16x8 v; } u;
        #pragma unroll
        for (int k = 0; k < 4; ++k) { u.h[k] = (f16)a[k]; u.h[k + 4] = (f16)b[k]; }
        *(f16x8*)(dst + (size_t)c * 8) = u.v;
    }
}

__global__ __launch_bounds__(512, 2) void attn_fwd(
    const float* __restrict__ Q, const f16* __restrict__ ws, float* __restrict__ Out)
{
    __shared__ __align__(16) char smem[SMEM_B];

    const int tid  = threadIdx.x;
    const int wv   = tid >> 6;
    const int grp  = wv >> 1;      // kv group 0..3 (512 kv each)
    const int qw   = wv & 1;       // q half (32 rows)
    const int lane = tid & 63;
    const int lrow = lane & 15;
    const int g    = lane >> 4;

    const int blk = blockIdx.x;
    const int b   = blk & 7;
    const int q0  = (blk >> 3) * 64;

    char* grpbase = smem + grp * (2 * TILE_B);

    // ---- Q fragments: single-pass fp16, pre-scaled by log2(e) ----
    f16x8 qh[2][4];
    {
        const float* qb = Q + ((size_t)b * L_DIM + q0 + qw * 32) * D_DIM;
        #pragma unroll
        for (int q2 = 0; q2 < 2; ++q2) {
            const float* qp = qb + (size_t)(q2 * 16 + lrow) * D_DIM + g * 8;
            #pragma unroll
            for (int dt = 0; dt < 4; ++dt) {
                f32x4 f0 = *(const f32x4*)(qp + dt * 32);
                f32x4 f1 = *(const f32x4*)(qp + dt * 32 + 4);
                #pragma unroll
                for (int i = 0; i < 4; ++i) {
                    qh[q2][dt][i]     = (f16)(f0[i] * LOG2E);
                    qh[q2][dt][i + 4] = (f16)(f1[i] * LOG2E);
                }
            }
        }
    }

    f32x4 acc[2][8];
    #pragma unroll
    for (int q2 = 0; q2 < 2; ++q2)
        #pragma unroll
        for (int i = 0; i < 8; ++i) acc[q2][i] = (f32x4)0.0f;
    float m_run[2] = { -3.0e38f, -3.0e38f }, l_run[2] = { 0.0f, 0.0f };

    // QK A-frag lane offset (bytes within tile)
    const int qkoff = (lrow >> 2) * 1024 + (g >> 1) * 128 + (lrow & 3) * 32 + (g & 1) * 16;

    const f16* wsb = ws + (size_t)b * (32 * KVB * D_DIM);   // this batch's ws slice

    // ---- prologue: DMA tile 0 into buf0 ----
    {
        const f16* w0 = wsb + (size_t)(grp * 8) * 8192 + (size_t)(qw * 512 + lane) * 8;
        char* ldst = grpbase + qw * 8192;
        #pragma unroll
        for (int i = 0; i < 8; ++i) GLDS(w0 + i * 512, ldst + i * 1024);
    }
    __syncthreads();

    for (int t = 0; t < NTILES; ++t) {
        const int c = t & 1;
        char* cur = grpbase + c * TILE_B;
        char* alt = grpbase + (c ^ 1) * TILE_B;

        // ---- QK^T swapped: S^T[kv 64][q 32], fp16 1-pass (log2e-scaled) ----
        f32x4 s[2][4];
        #pragma unroll
        for (int q2 = 0; q2 < 2; ++q2)
            #pragma unroll
            for (int nt = 0; nt < 4; ++nt) s[q2][nt] = (f32x4)0.0f;
        __builtin_amdgcn_s_setprio(1);
        #pragma unroll
        for (int nt = 0; nt < 4; ++nt) {
            #pragma unroll
            for (int dt = 0; dt < 4; ++dt) {
                f16x8 a = *(const f16x8*)(cur + qkoff + nt * 4096 + dt * 256);
                s[0][nt] = MFMA16(a, qh[0][dt], s[0][nt]);
                s[1][nt] = MFMA16(a, qh[1][dt], s[1][nt]);
            }
        }
        __builtin_amdgcn_s_setprio(0);

        // ---- online softmax with defer-max (THR=11.5 in log2 units) ----
        float pm[2];
        #pragma unroll
        for (int q2 = 0; q2 < 2; ++q2) {
            float tm = s[q2][0][0];
            #pragma unroll
            for (int nt = 0; nt < 4; ++nt)
                #pragma unroll
                for (int r = 0; r < 4; ++r) tm = fmaxf(tm, s[q2][nt][r]);
            tm = pl16_max(tm);
            tm = pl32_max(tm);
            pm[q2] = tm;
        }
        bool need = (pm[0] > m_run[0] + 11.5f) || (pm[1] > m_run[1] + 11.5f);
        if (__any(need)) {
            float scl[2];
            #pragma unroll
            for (int q2 = 0; q2 < 2; ++q2) {
                float mnew = fmaxf(m_run[q2], pm[q2]);
                scl[q2]  = EXP2(m_run[q2] - mnew);
                m_run[q2] = mnew;
                l_run[q2] *= scl[q2];
            }
            float sr[2][4];
            #pragma unroll
            for (int r = 0; r < 4; ++r) {
                sr[0][r] = __shfl(scl[0], g * 4 + r);
                sr[1][r] = __shfl(scl[1], g * 4 + r);
            }
            #pragma unroll
            for (int q2 = 0; q2 < 2; ++q2)
                #pragma unroll
                for (int nd = 0; nd < 8; ++nd)
                    #pragma unroll
                    for (int r = 0; r < 4; ++r) acc[q2][nd][r] *= sr[q2][r];
        }
        #pragma unroll
        for (int q2 = 0; q2 < 2; ++q2) {
            float ps = 0.0f;
            #pragma unroll
            for (int nt = 0; nt < 4; ++nt)
                #pragma unroll
                for (int r = 0; r < 4; ++r) {
                    float p = EXP2(s[q2][nt][r] - m_run[q2]);
                    s[q2][nt][r] = p;
                    ps += p;
                }
            ps = pl16_add(ps);
            ps = pl32_add(ps);
            l_run[q2] += ps;
        }

        // ---- P -> A-frags fully in-register via permlane swaps (R21-verified) ----
        f16x8 pa00, pa01, pa10, pa11;
        {
            unsigned y0[4][2], y1[4][2];
            #pragma unroll
            for (int nt = 0; nt < 4; ++nt) {
                y0[nt][0] = pkh(s[0][nt][0], s[0][nt][1]);
                y0[nt][1] = pkh(s[0][nt][2], s[0][nt][3]);
                y1[nt][0] = pkh(s[1][nt][0], s[1][nt][1]);
                y1[nt][1] = pkh(s[1][nt][2], s[1][nt][3]);
            }
            union U8 { unsigned w[4]; f16x8 v; };
            U8 a00, a01, a10, a11;
            #pragma unroll
            for (int h = 0; h < 2; ++h) {
                uint2v t1 = __builtin_amdgcn_permlane32_swap(y0[0][h], y0[1][h], false, false);
                uint2v t2 = __builtin_amdgcn_permlane16_swap(t1[0], t1[1], false, false);
                a00.w[h] = t2[0]; a00.w[2 + h] = t2[1];
                uint2v t3 = __builtin_amdgcn_permlane32_swap(y0[2][h], y0[3][h], false, false);
                uint2v t4 = __builtin_amdgcn_permlane16_swap(t3[0], t3[1], false, false);
                a01.w[h] = t4[0]; a01.w[2 + h] = t4[1];
                uint2v t5 = __builtin_amdgcn_permlane32_swap(y1[0][h], y1[1][h], false, false);
                uint2v t6 = __builtin_amdgcn_permlane16_swap(t5[0], t5[1], false, false);
                a10.w[h] = t6[0]; a10.w[2 + h] = t6[1];
                uint2v t7 = __builtin_amdgcn_permlane32_swap(y1[2][h], y1[3][h], false, false);
                uint2v t8 = __builtin_amdgcn_permlane16_swap(t7[0], t7[1], false, false);
                a11.w[h] = t8[0]; a11.w[2 + h] = t8[1];
            }
            pa00 = a00.v; pa01 = a01.v; pa10 = a10.v; pa11 = a11.v;
        }

        // ---- issue DMA staging of tile t+1 into alt (alt dead since PV(t-1)) ----
        if (t + 1 < NTILES) {
            const f16* wnt = wsb + (size_t)(grp * 8 + t + 1) * 8192 + (size_t)(qw * 512 + lane) * 8;
            char* ldst = alt + qw * 8192;
            #pragma unroll
            for (int i = 0; i < 8; ++i) GLDS(wnt + i * 512, ldst + i * 1024);
        }

        // ---- PV: software-pipelined tr-reads with counted lgkm waits (<=15!);
        //      16 reads in flight max; each group's latency hides under prev MFMAs ----
        {
            unsigned atr0 = ldsa(cur) + (unsigned)(g * 2048 + lrow * 8);
            unsigned atr1 = atr0 + 8192u;
            s16x4 ta[8], tb[8], tc[8], td[8];
            TR8(ta, atr0, "0","1024","128","1152","256","1280","384","1408");
            TR8(tb, atr0, "512","1536","640","1664","768","1792","896","1920");
            LGKMW(8);                       // ta complete (tb in flight)
            MM8(ta, pa00, pa10, 0);
            TR8(tc, atr1, "0","1024","128","1152","256","1280","384","1408");
            LGKMW(8);                       // tb complete (tc in flight)
            MM8(tb, pa00, pa10, 4);
            TR8(td, atr1, "512","1536","640","1664","768","1792","896","1920");
            LGKMW(8);                       // tc complete (td in flight)
            MM8(tc, pa01, pa11, 0);
            LGKMW(0);                       // td complete
            MM8(td, pa01, pa11, 4);
        }

        __syncthreads();   // drains vmcnt (DMA) + lgkm; next iter reads alt
    }

    // ---- cross-group merge (smem repurposed after final barrier) ----
    float* slab = (float*)smem;                          // [8 waves][32 q][SLAB_ST]
    float* mlp  = (float*)(smem + 8 * 32 * SLAB_ST * 4); // [8 waves][2][32]
    #pragma unroll
    for (int q2 = 0; q2 < 2; ++q2)
        #pragma unroll
        for (int nd = 0; nd < 8; ++nd)
            #pragma unroll
            for (int r = 0; r < 4; ++r)
                slab[(size_t)(wv * 32 + q2 * 16 + g * 4 + r) * SLAB_ST + nd * 16 + lrow] = acc[q2][nd][r];
    if (g == 0) {
        #pragma unroll
        for (int q2 = 0; q2 < 2; ++q2) {
            mlp[wv * 64 + q2 * 16 + lrow]      = m_run[q2];
            mlp[wv * 64 + 32 + q2 * 16 + lrow] = l_run[q2];
        }
    }
    __syncthreads();

    #pragma unroll
    for (int rr = 0; rr < 8; ++rr) {
        int row = wv * 8 + rr;
        int qws = row >> 5, ql = row & 31;
        float mg[4], M = -3.0e38f;
        #pragma unroll
        for (int gg = 0; gg < 4; ++gg) {
            mg[gg] = mlp[(gg * 2 + qws) * 64 + ql];
            M = fmaxf(M, mg[gg]);
        }
        float L = 0.0f, f[4];
        #pragma unroll
        for (int gg = 0; gg < 4; ++gg) {
            f[gg] = EXP2(mg[gg] - M);
            L += f[gg] * mlp[(gg * 2 + qws) * 64 + 32 + ql];
        }
        float inv = 1.0f / L;
        f32x2 o = { 0.0f, 0.0f };
        #pragma unroll
        for (int gg = 0; gg < 4; ++gg) {
            f32x2 v = *(const f32x2*)&slab[(size_t)((gg * 2 + qws) * 32 + ql) * SLAB_ST + lane * 2];
            o[0] += f[gg] * v[0];
            o[1] += f[gg] * v[1];
        }
        o[0] *= inv; o[1] *= inv;
        *(f32x2*)&Out[((size_t)b * L_DIM + q0 + row) * D_DIM + lane * 2] = o;
    }
}

extern "C" void kernel_launch(void* const* d_in, const int* in_sizes, int n_in,
                              void* d_out, int out_size, void* d_ws, size_t ws_size,
                              hipStream_t stream) {
    const float* Q = (const float*)d_in[0];
    const float* V = (const float*)d_in[1];
    float* Out     = (float*)d_out;
    f16* ws        = (f16*)d_ws;   // needs 4 MiB
    prep_v<<<dim3(B_DIM * (L_DIM / KVB)), dim3(256), 0, stream>>>(V, ws);
    attn_fwd<<<dim3(B_DIM * (L_DIM / 64)), dim3(512), 0, stream>>>(Q, ws, Out);
}